// Round 6
// baseline (209.148 us; speedup 1.0000x reference)
//
#include <hip/hip_runtime.h>
#include <math.h>

#define N_NODES 50000
#define N_EDGES 800000
#define TGT     (N_NODES - 1)
#define C2MAX   256            // cap on in-degree of TGT (E[deg]=16)
#define KCAP    258            // max unique layer-1 dst nodes
#define ELMAX   256            // per-dst layer-1 edge cap
#define ROWS    (ELMAX + 1)
#define GRID    256            // 1 block/CU -- capacity-guaranteed co-resident
#define JPAD    32             // per-dst counter stride (128B: one cacheline each)
#define NLEAF   16             // barrier leaves (separate cachelines)
#define LPB     (GRID / NLEAF) // arrivals per leaf
#define BAR0    64             // int offset of the (single) barrier area in cnt[]
#define BARROOT 512            // root offset within the barrier area
#define BARFLAG 576            // flag offset within the barrier area

// ---------------- workspace carve ----------------
struct WS {
  int* cnt;      // [2048]: [0]=#edges into TGT, [1]=global F-join; barrier at BAR0
  int* cnt2;     // [KCAP*JPAD] per-dst edge counters, line-padded   (memset 0)
  int* fin_k;    // [KCAP*JPAD] per-dst group-join counters, padded  (memset 0)
  int* e2src;    // [C2MAX]
  int* l1src;    // [KCAP*ELMAX]
  float* W1T4;   // [65536]  layout: ((c>>2)*256 + o)*4 + (c&3)
  float* W2T4;   // [65536]
  float* g_xw2;  // [KCAP*256]
  float* g_as2;  // [KCAP*8]
  float* g_ad2;  // [KCAP*8]
  float* g_xw1;  // [KCAP*ROWS*256]  (winner-block private use)
};
__host__ __device__ inline WS carve(char* ws) {
  WS w; int* p = (int*)ws;
  w.cnt = p;    p += 2048;
  w.cnt2 = p;   p += KCAP * JPAD;
  w.fin_k = p;  p += KCAP * JPAD;
  w.e2src = p;  p += C2MAX;
  w.l1src = p;  p += KCAP * ELMAX;
  float* f = (float*)p;
  w.W1T4 = f;   f += 65536;
  w.W2T4 = f;   f += 65536;
  w.g_xw2 = f;  f += KCAP * 256;
  w.g_as2 = f;  f += KCAP * 8;
  w.g_ad2 = f;  f += KCAP * 8;
  w.g_xw1 = f;
  return w;
}

// One-shot hierarchical grid barrier (R3/R5-verified). 16 leaf lines, 16 root
// RMWs, one release flag; RELAXED spin (no per-poll cache inv); one acquire
// fence per block. Bounded spin so a residency surprise degrades, not hangs.
__device__ inline void gbar(int* cnt, int base, int blk) {
  __syncthreads();
  if (threadIdx.x == 0) {
    int* leaf = cnt + base + (blk & (NLEAF - 1)) * 32;
    int* root = cnt + base + BARROOT;
    int* flag = cnt + base + BARFLAG;
    int lv = __hip_atomic_fetch_add(leaf, 1, __ATOMIC_ACQ_REL, __HIP_MEMORY_SCOPE_AGENT);
    if (lv == LPB - 1) {
      int rv = __hip_atomic_fetch_add(root, 1, __ATOMIC_ACQ_REL, __HIP_MEMORY_SCOPE_AGENT);
      if (rv == NLEAF - 1)
        __hip_atomic_store(flag, 1, __ATOMIC_RELEASE, __HIP_MEMORY_SCOPE_AGENT);
    }
    int spins = 0;
    while (__hip_atomic_load(flag, __ATOMIC_RELAXED, __HIP_MEMORY_SCOPE_AGENT) == 0) {
      __builtin_amdgcn_s_sleep(4);
      if (++spins > (1 << 22)) break;          // escape hatch
    }
    __builtin_amdgcn_fence(__ATOMIC_ACQUIRE, "agent");
  }
  __syncthreads();
}

__global__ __launch_bounds__(256, 2) void k_all(
    const float* __restrict__ x, const int* __restrict__ eidx,
    const float* __restrict__ W1, const float* __restrict__ W2,
    const float* __restrict__ aS1, const float* __restrict__ aD1,
    const float* __restrict__ b1, const float* __restrict__ aS2,
    const float* __restrict__ aD2, const float* __restrict__ b2,
    float* __restrict__ out, char* __restrict__ ws)
{
  WS w = carve(ws);
  const int t = threadIdx.x;
  const int blk = blockIdx.x;
  const int tid = blk * 256 + t;
  const int nthreads = GRID * 256;

  // persistent LDS (survives all stages; every block keeps the dedup result
  // so any winner can run E/F)
  __shared__ int s_kv[2];          // [0]=K1, [1]=kd
  __shared__ int s_uniq[KCAP];
  __shared__ int s_slotp[C2MAX];
  __shared__ int s_winE, s_winF;
  __shared__ __align__(16) char smem[28800];  // per-stage overlay

  // ========== stage A: W transpose + TGT edge scan ==========
  if (blk < 32) {                              // 2 matrices x 16 tiles of 64x64
    float (*lds)[65] = (float(*)[65])smem;
    int m  = blk >> 4;
    int ti = (blk >> 2) & 3, tj = blk & 3;
    const float* src = m ? W2 : W1;
    float*       dst = m ? w.W2T4 : w.W1T4;
    int r0 = t >> 6, cc = t & 63;
    float tmp[16];
#pragma unroll
    for (int p = 0; p < 16; ++p)               // 16 independent coalesced loads
      tmp[p] = src[(ti * 64 + p * 4 + r0) * 256 + tj * 64 + cc];
#pragma unroll
    for (int p = 0; p < 16; ++p)
      lds[p * 4 + r0][cc] = tmp[p];
    __syncthreads();
    int c40 = t >> 6, o = t & 63;
#pragma unroll
    for (int p2 = 0; p2 < 4; ++p2) {           // coalesced float4 writes
      int c4l = p2 * 4 + c40;
      float4 v = make_float4(lds[o][4 * c4l + 0], lds[o][4 * c4l + 1],
                             lds[o][4 * c4l + 2], lds[o][4 * c4l + 3]);
      ((float4*)dst)[(tj * 16 + c4l) * 256 + ti * 64 + o] = v;
    }
  }
  {
    const int* esrc = eidx;
    const int4* edst4 = (const int4*)(eidx + N_EDGES);
    for (int i = tid; i < N_EDGES / 4; i += nthreads) {
      int4 d = edst4[i];
      int dv[4] = {d.x, d.y, d.z, d.w};
#pragma unroll
      for (int j = 0; j < 4; ++j)
        if (dv[j] == TGT) {
          int p = atomicAdd(&w.cnt[0], 1);
          if (p < C2MAX) w.e2src[p] = esrc[4 * i + j];
        }
    }
  }
  gbar(w.cnt, BAR0, blk);                      // the ONLY grid barrier

  // ========== per-block dedup (kept in LDS) ==========
  {
    int* s_e = (int*)smem;                       // 256 ints
    int* s_scan = (int*)(smem + 1024);           // 256 ints
    int c2 = min(w.cnt[0], C2MAX);
    if (t < c2) s_e[t] = w.e2src[t];
    __syncthreads();
    int firstIdx = t;
    if (t < c2) {
      int s = s_e[t];
      for (int q = 0; q < t; ++q) if (s_e[q] == s) { firstIdx = q; break; }
    }
    s_scan[t] = (t < c2 && firstIdx == t) ? 1 : 0;
    __syncthreads();
    for (int off = 1; off < 256; off <<= 1) {
      int add = (t >= off) ? s_scan[t - off] : 0;
      __syncthreads();
      s_scan[t] += add;
      __syncthreads();
    }
    if (t < c2 && firstIdx == t) s_uniq[s_scan[t] - 1] = s_e[t];
    __syncthreads();
    if (t < c2) s_slotp[t] = s_scan[firstIdx] - 1;
    if (t == 0) {
      int K1 = (c2 > 0) ? s_scan[255] : 0;
      int kd = -1;
      for (int i = 0; i < K1; ++i) if (s_uniq[i] == TGT) { kd = i; break; }
      if (kd < 0) { s_uniq[K1] = TGT; kd = K1; K1++; }
      s_kv[0] = K1; s_kv[1] = kd;
    }
    __syncthreads();
  }

  // ========== group scan: ~GRID/K1 blocks per dst, single-compare match ====
  const int K1 = s_kv[0];
  const int K1m = min(K1, GRID);
  const int gk = blk % K1m;                    // my dst group
  const int gs = blk / K1m;                    // my slice within the group
  const int gS = (GRID - 1 - gk) / K1m + 1;    // blocks in my group
  {
    const int myk_node = s_uniq[gk];
    const int* esrc = eidx;
    const int4* edst4 = (const int4*)(eidx + N_EDGES);
    for (int i = gs * 256 + t; i < N_EDGES / 4; i += gS * 256) {
      int4 d = edst4[i];
      int dv[4] = {d.x, d.y, d.z, d.w};
#pragma unroll
      for (int j = 0; j < 4; ++j)
        if (dv[j] == myk_node) {
          int p = atomicAdd(&w.cnt2[gk * JPAD], 1);
          if (p < ELMAX) w.l1src[gk * ELMAX + p] = esrc[4 * i + j];
        }
    }
  }

  // ---- per-dst group join (R3-verified idiom, line-padded counters) ----
  __syncthreads();
  if (t == 0) {
    __threadfence();
    int old = __hip_atomic_fetch_add(&w.fin_k[gk * JPAD], 1, __ATOMIC_ACQ_REL, __HIP_MEMORY_SCOPE_AGENT);
    s_winE = (old == gS - 1);
  }
  __syncthreads();

  // ========== stages D+E (+F join) for my dst(s) ==========
  const float4* W1v = (const float4*)w.W1T4;
  const float4* W2v = (const float4*)w.W2T4;
  for (int pass = 0; pass < 2; ++pass) {
    int kk; bool active;
    if (pass == 0) { kk = gk; active = (s_winE != 0); }
    else {
      kk = blk + GRID; active = (kk < K1);     // cold path: K1 > GRID (<=257)
      if (active) {                            // solo scan for the overflow dst
        int node2 = s_uniq[kk];
        const int* esrc = eidx;
        const int4* edst4 = (const int4*)(eidx + N_EDGES);
        for (int i = t; i < N_EDGES / 4; i += 256) {
          int4 d = edst4[i];
          int dv[4] = {d.x, d.y, d.z, d.w};
#pragma unroll
          for (int j = 0; j < 4; ++j)
            if (dv[j] == node2) {
              int p = atomicAdd(&w.cnt2[kk * JPAD], 1);
              if (p < ELMAX) w.l1src[kk * ELMAX + p] = esrc[4 * i + j];
            }
        }
        __syncthreads();
      }
    }
    if (active) {
      if (pass == 0) __threadfence();          // acquire peers' l1src stores
      const int ne = min((int)__hip_atomic_load(&w.cnt2[kk * JPAD], __ATOMIC_RELAXED,
                                                __HIP_MEMORY_SCOPE_AGENT), ELMAX);
      const int items = ne + 1;                // edges + the dst node itself
      const int myNode = s_uniq[kk];

      float* s_xsT = (float*)smem;             // 1024 f
      float* s_redS = (float*)(smem + 4096);   // 1024 f
      float* s_redD = (float*)(smem + 8192);   // 1024 f
      float* s_as1 = (float*)(smem + 12288);   // ROWS*8 f (persists into E)
      float* s_ad1 = (float*)(smem + 20512);   // ROWS*8 f (persists into E)
      const float4* xsT4 = (const float4*)s_xsT;

      // ---- stage D: all row-batches of this dst, sequential in one block ----
      for (int base = 0; base < items; base += 4) {
        int na = min(4, items - base);
        int nd[4];
#pragma unroll
        for (int i = 0; i < 4; ++i) {          // 4 independent index loads
          int it = base + i;
          nd[i] = (it < ne) ? w.l1src[kk * ELMAX + it] : myNode;
        }
#pragma unroll
        for (int i = 0; i < 4; ++i)            // 4 independent row loads in flight
          s_xsT[t * 4 + i] = x[(size_t)nd[i] * 256 + t];
        __syncthreads();
        float a0 = 0.f, a1 = 0.f, a2 = 0.f, a3 = 0.f;
        for (int cc = 0; cc < 64; cc += 8) {
          float4 wreg[8];
#pragma unroll
          for (int j = 0; j < 8; ++j)          // 8 W loads issued before any use
            wreg[j] = W1v[(size_t)(cc + j) * 256 + t];
#pragma unroll
          for (int j = 0; j < 8; ++j) {
            float4 wv = wreg[j];
            int c4 = cc + j;
            float4 x0 = xsT4[4 * c4 + 0];
            float4 x1 = xsT4[4 * c4 + 1];
            float4 x2 = xsT4[4 * c4 + 2];
            float4 x3 = xsT4[4 * c4 + 3];
            a0 = fmaf(wv.x, x0.x, a0); a0 = fmaf(wv.y, x1.x, a0); a0 = fmaf(wv.z, x2.x, a0); a0 = fmaf(wv.w, x3.x, a0);
            a1 = fmaf(wv.x, x0.y, a1); a1 = fmaf(wv.y, x1.y, a1); a1 = fmaf(wv.z, x2.y, a1); a1 = fmaf(wv.w, x3.y, a1);
            a2 = fmaf(wv.x, x0.z, a2); a2 = fmaf(wv.y, x1.z, a2); a2 = fmaf(wv.z, x2.z, a2); a2 = fmaf(wv.w, x3.z, a2);
            a3 = fmaf(wv.x, x0.w, a3); a3 = fmaf(wv.y, x1.w, a3); a3 = fmaf(wv.z, x2.w, a3); a3 = fmaf(wv.w, x3.w, a3);
          }
        }
        float accs[4] = {a0, a1, a2, a3};
        for (int i = 0; i < na; ++i) {
          w.g_xw1[(size_t)(kk * ROWS + base + i) * 256 + t] = accs[i];  // own-block reuse
          s_redS[i * 256 + t] = accs[i] * aS1[t];
          s_redD[i * 256 + t] = accs[i] * aD1[t];
        }
        __syncthreads();
        if (t < 32) {
          int i = t >> 3, h = t & 7;
          if (i < na) {
            float s = 0.f, dd = 0.f;
            for (int q = 0; q < 32; ++q) {
              s  += s_redS[i * 256 + h * 32 + q];
              dd += s_redD[i * 256 + h * 32 + q];
            }
            s_as1[(base + i) * 8 + h] = s;     // LDS, no global round-trip
            s_ad1[(base + i) * 8 + h] = dd;
          }
        }
        __syncthreads();
      }

      // ---- stage E: softmax + aggregate + bias + exact GELU + xw2 ----
      {
        float* s_p  = (float*)smem;            // 2048 f (overlays s_xsT+s_redS)
        float* s_h1 = (float*)(smem + 10240);  // 256 f (align 16)
        float* s_den = (float*)(smem + 11264); // 8 f
        if (t < 8) {
          int h = t;
          float adst = s_ad1[ne * 8 + h];
          float m = -INFINITY;
          for (int j = 0; j < ne; ++j) {
            float e = s_as1[j * 8 + h] + adst;
            e = (e >= 0.f) ? e : 0.2f * e;
            m = fmaxf(m, e);
          }
          float den = 0.f;
          for (int j = 0; j < ne; ++j) {
            float e = s_as1[j * 8 + h] + adst;
            e = (e >= 0.f) ? e : 0.2f * e;
            float pp = expf(e - m);
            s_p[j * 8 + h] = pp;
            den += pp;
          }
          s_den[h] = den + 1e-16f;
        }
        __syncthreads();
        int h = t >> 5;
        float acc = 0.f;
        const float* xwb = w.g_xw1 + (size_t)(kk * ROWS) * 256 + t;  // own writes
        for (int j0 = 0; j0 < ne; j0 += 8) {
          float tmp[8];
#pragma unroll
          for (int j = 0; j < 8; ++j)          // 8 gathers in flight
            tmp[j] = (j0 + j < ne) ? xwb[(size_t)(j0 + j) * 256] : 0.f;
#pragma unroll
          for (int j = 0; j < 8; ++j)
            if (j0 + j < ne) acc = fmaf(s_p[(j0 + j) * 8 + h], tmp[j], acc);
        }
        float o = (ne > 0) ? acc / s_den[h] : 0.f;
        o += b1[t];
        s_h1[t] = 0.5f * o * (1.f + erff(o * 0.70710678118654752440f));  // exact GELU
        __syncthreads();
        float a2s = 0.f;
        const float4* h1v = (const float4*)s_h1;
        for (int cc = 0; cc < 64; cc += 8) {
          float4 wreg[8];
#pragma unroll
          for (int j = 0; j < 8; ++j)
            wreg[j] = W2v[(size_t)(cc + j) * 256 + t];
#pragma unroll
          for (int j = 0; j < 8; ++j) {
            float4 wv = wreg[j];
            float4 hv = h1v[cc + j];
            a2s = fmaf(wv.x, hv.x, a2s); a2s = fmaf(wv.y, hv.y, a2s);
            a2s = fmaf(wv.z, hv.z, a2s); a2s = fmaf(wv.w, hv.w, a2s);
          }
        }
        w.g_xw2[kk * 256 + t] = a2s;
        float* rS = (float*)(smem + 8192);     // free by now (s_redD region)
        float* rD = (float*)(smem + 9216);
        rS[t] = a2s * aS2[t];
        rD[t] = a2s * aD2[t];
        __syncthreads();
        if (t < 8) {
          float s = 0.f, dd = 0.f;
          for (int q = 0; q < 32; ++q) { s += rS[t * 32 + q]; dd += rD[t * 32 + q]; }
          w.g_as2[kk * 8 + t] = s;
          w.g_ad2[kk * 8 + t] = dd;
        }
      }

      // ---- global join (verified idiom): K1-th finished dst runs stage F ----
      __syncthreads();
      if (t == 0) {
        __threadfence();
        int old2 = __hip_atomic_fetch_add(&w.cnt[1], 1, __ATOMIC_ACQ_REL, __HIP_MEMORY_SCOPE_AGENT);
        s_winF = (old2 == K1 - 1);
      }
      __syncthreads();
      if (s_winF) {
        __threadfence();
        // ---- stage F: layer-2 attention for node TGT ----
        float* s_p = (float*)smem;             // 2048 f
        float* s_den = (float*)(smem + 8192);  // 8 f
        int c2 = min(w.cnt[0], C2MAX);
        int kd = s_kv[1];
        if (t < 8) {
          float adst = w.g_ad2[kd * 8 + t];
          float m = -INFINITY;
          for (int j = 0; j < c2; ++j) {
            float e = w.g_as2[s_slotp[j] * 8 + t] + adst;
            e = (e >= 0.f) ? e : 0.2f * e;
            m = fmaxf(m, e);
          }
          float den = 0.f;
          for (int j = 0; j < c2; ++j) {
            float e = w.g_as2[s_slotp[j] * 8 + t] + adst;
            e = (e >= 0.f) ? e : 0.2f * e;
            float pp = expf(e - m);
            s_p[j * 8 + t] = pp;
            den += pp;
          }
          s_den[t] = den + 1e-16f;
        }
        __syncthreads();
        int h = t >> 5;
        float acc2 = 0.f;
        for (int j0 = 0; j0 < c2; j0 += 8) {
          float tmp[8];
#pragma unroll
          for (int j = 0; j < 8; ++j)
            tmp[j] = (j0 + j < c2) ? w.g_xw2[s_slotp[j0 + j] * 256 + t] : 0.f;
#pragma unroll
          for (int j = 0; j < 8; ++j)
            if (j0 + j < c2) acc2 = fmaf(s_p[(j0 + j) * 8 + h], tmp[j], acc2);
        }
        float o2 = (c2 > 0) ? acc2 / s_den[h] : 0.f;
        out[t] = o2 + b2[t];
      }
    }
    __syncthreads();                           // protect overlay between passes
  }
}

extern "C" void kernel_launch(void* const* d_in, const int* in_sizes, int n_in,
                              void* d_out, int out_size, void* d_ws, size_t ws_size,
                              hipStream_t stream) {
  const float* x    = (const float*)d_in[0];
  const int*   eidx = (const int*)d_in[1];
  const float* W1   = (const float*)d_in[2];
  const float* aS1  = (const float*)d_in[3];
  const float* aD1  = (const float*)d_in[4];
  const float* b1   = (const float*)d_in[5];
  const float* W2   = (const float*)d_in[6];
  const float* aS2  = (const float*)d_in[7];
  const float* aD2  = (const float*)d_in[8];
  const float* b2   = (const float*)d_in[9];
  float* out = (float*)d_out;
  char*  ws  = (char*)d_ws;

  // zero cnt[2048] (incl. barrier area) + padded cnt2 + padded fin_k
  hipMemsetAsync(ws, 0, (2048 + 2 * KCAP * JPAD) * sizeof(int), stream);

  k_all<<<dim3(GRID), dim3(256), 0, stream>>>(x, eidx, W1, W2, aS1, aD1, b1,
                                              aS2, aD2, b2, out, ws);
}

// Round 7
// 177.421 us; speedup vs baseline: 1.1788x; 1.1788x over previous
//
#include <hip/hip_runtime.h>
#include <math.h>

#define N_NODES 50000
#define N_EDGES 800000
#define TGT     (N_NODES - 1)
#define C2MAX   256            // cap on in-degree of TGT (E[deg]=16)
#define KCAP    258            // max unique layer-1 dst nodes
#define ELMAX   256            // per-dst layer-1 edge cap
#define ROWS    (ELMAX + 1)
#define GRID    256            // 1 block/CU -- capacity-guaranteed co-resident
#define BMWORDS 1568           // ceil(50000/32)=1563, rounded
#define NLEAF   16             // barrier leaves (separate cachelines)
#define LPB     (GRID / NLEAF) // arrivals per leaf
#define BAR0    64             // int offsets of barrier areas inside cnt[]
#define BAR1    704
#define BARROOT 512            // root offset within a barrier area
#define BARFLAG 576            // flag offset within a barrier area

// ---------------- workspace carve ----------------
struct WS {
  int* cnt;      // [2048]: [0]=#edges into TGT, [1]=global F-join; barriers at BAR0/BAR1
  int* cnt2;     // [272] per-dst-slot edge counters           (memset 0)
  int* fin_k;    // [272] unused (layout kept)                 (memset 0)
  int* e2src;    // [C2MAX]
  int* l1src;    // [KCAP*ELMAX]
  float* W1T4;   // [65536]  layout: ((c>>2)*256 + o)*4 + (c&3)
  float* W2T4;   // [65536]
  float* g_xw2;  // [KCAP*256]
  float* g_as2;  // [KCAP*8]
  float* g_ad2;  // [KCAP*8]
  float* g_xw1;  // [KCAP*ROWS*256]  (winner-block private use)
};
__host__ __device__ inline WS carve(char* ws) {
  WS w; int* p = (int*)ws;
  w.cnt = p;    p += 2048;
  w.cnt2 = p;   p += 272;
  w.fin_k = p;  p += 272;
  w.e2src = p;  p += C2MAX;
  w.l1src = p;  p += KCAP * ELMAX;
  float* f = (float*)p;
  w.W1T4 = f;   f += 65536;
  w.W2T4 = f;   f += 65536;
  w.g_xw2 = f;  f += KCAP * 256;
  w.g_as2 = f;  f += KCAP * 8;
  w.g_ad2 = f;  f += KCAP * 8;
  w.g_xw1 = f;
  return w;
}

// RELAXED hierarchical grid barrier. R6 lesson (WRITE_SIZE 44MB): every
// agent-scope ACQ_REL RMW emits buffer_wbl2 and every acquire fence emits
// buffer_inv -- ~1000 L2 walks were the hidden ~75us in R5. Here ALL barrier
// atomics are RELAXED (plain coherence-point ops, no cache maintenance).
// Safety: gbar's leading __syncthreads drains each wave's stores (HIP emits
// vmcnt(0) before s_barrier); sc1/atomic data is already at the coherence
// point; cached producers (blocks 0-31) pass flush=true for ONE release
// fence (wbl2, no inv) covering their W1T4/W2T4 writes. No exit acquire:
// consumers' reads of cross-block data are first-touch in their L2 this
// launch (dispatch-start invalidate), so they fetch fresh from L3.
__device__ inline void gbar(int* cnt, int base, int blk, bool flush) {
  __syncthreads();
  if (threadIdx.x == 0) {
    if (flush)
      __builtin_amdgcn_fence(__ATOMIC_RELEASE, "agent");   // wbl2 only, 32 blocks
    int* leaf = cnt + base + (blk & (NLEAF - 1)) * 32;
    int* root = cnt + base + BARROOT;
    int* flag = cnt + base + BARFLAG;
    int lv = __hip_atomic_fetch_add(leaf, 1, __ATOMIC_RELAXED, __HIP_MEMORY_SCOPE_AGENT);
    if (lv == LPB - 1) {
      int rv = __hip_atomic_fetch_add(root, 1, __ATOMIC_RELAXED, __HIP_MEMORY_SCOPE_AGENT);
      if (rv == NLEAF - 1)
        __hip_atomic_store(flag, 1, __ATOMIC_RELAXED, __HIP_MEMORY_SCOPE_AGENT);
    }
    int spins = 0;
    while (__hip_atomic_load(flag, __ATOMIC_RELAXED, __HIP_MEMORY_SCOPE_AGENT) == 0) {
      __builtin_amdgcn_s_sleep(4);
      if (++spins > (1 << 22)) break;          // escape hatch
    }
  }
  __syncthreads();
}

__global__ __launch_bounds__(256, 2) void k_all(
    const float* __restrict__ x, const int* __restrict__ eidx,
    const float* __restrict__ W1, const float* __restrict__ W2,
    const float* __restrict__ aS1, const float* __restrict__ aD1,
    const float* __restrict__ b1, const float* __restrict__ aS2,
    const float* __restrict__ aD2, const float* __restrict__ b2,
    float* __restrict__ out, char* __restrict__ ws)
{
  WS w = carve(ws);
  const int t = threadIdx.x;
  const int blk = blockIdx.x;
  const int tid = blk * 256 + t;
  const int nthreads = GRID * 256;

  // persistent LDS (survives all stages; every block keeps the dedup result
  // so any block can win the F join)
  __shared__ int s_kv[2];          // [0]=K1, [1]=kd
  __shared__ int s_uniq[KCAP];
  __shared__ int s_slotp[C2MAX];
  __shared__ int s_winF;
  __shared__ __align__(16) char smem[28800];  // per-stage overlay

  // ========== stage A: W transpose + TGT edge scan ==========
  if (blk < 32) {                              // 2 matrices x 16 tiles of 64x64
    float (*lds)[65] = (float(*)[65])smem;
    int m  = blk >> 4;
    int ti = (blk >> 2) & 3, tj = blk & 3;
    const float* src = m ? W2 : W1;
    float*       dst = m ? w.W2T4 : w.W1T4;
    int r0 = t >> 6, cc = t & 63;
    float tmp[16];
#pragma unroll
    for (int p = 0; p < 16; ++p)               // 16 independent coalesced loads
      tmp[p] = src[(ti * 64 + p * 4 + r0) * 256 + tj * 64 + cc];
#pragma unroll
    for (int p = 0; p < 16; ++p)
      lds[p * 4 + r0][cc] = tmp[p];
    __syncthreads();
    int c40 = t >> 6, o = t & 63;
#pragma unroll
    for (int p2 = 0; p2 < 4; ++p2) {           // coalesced float4 writes
      int c4l = p2 * 4 + c40;
      float4 v = make_float4(lds[o][4 * c4l + 0], lds[o][4 * c4l + 1],
                             lds[o][4 * c4l + 2], lds[o][4 * c4l + 3]);
      ((float4*)dst)[(tj * 16 + c4l) * 256 + ti * 64 + o] = v;
    }
  }
  {
    const int* esrc = eidx;
    const int4* edst4 = (const int4*)(eidx + N_EDGES);
    for (int i = tid; i < N_EDGES / 4; i += nthreads) {
      int4 d = edst4[i];
      int dv[4] = {d.x, d.y, d.z, d.w};
#pragma unroll
      for (int j = 0; j < 4; ++j)
        if (dv[j] == TGT) {
          int p = atomicAdd(&w.cnt[0], 1);
          if (p < C2MAX)                       // write-through: no release needed
            __hip_atomic_store(&w.e2src[p], esrc[4 * i + j],
                               __ATOMIC_RELAXED, __HIP_MEMORY_SCOPE_AGENT);
        }
    }
  }
  gbar(w.cnt, BAR0, blk, blk < 32);            // only W-producers flush

  // ========== stage C: per-block dedup (kept in LDS) + bucket scan ==========
  {
    int* s_e = (int*)smem;                       // 256 ints
    int* s_scan = (int*)(smem + 1024);           // 256 ints
    unsigned* s_bm = (unsigned*)(smem + 2048);   // 1568 words
    int c2 = min(w.cnt[0], C2MAX);
    if (t < c2) s_e[t] = w.e2src[t];             // first-touch read -> L3, fresh
    __syncthreads();
    int firstIdx = t;
    if (t < c2) {
      int s = s_e[t];
      for (int q = 0; q < t; ++q) if (s_e[q] == s) { firstIdx = q; break; }
    }
    s_scan[t] = (t < c2 && firstIdx == t) ? 1 : 0;
    __syncthreads();
    for (int off = 1; off < 256; off <<= 1) {
      int add = (t >= off) ? s_scan[t - off] : 0;
      __syncthreads();
      s_scan[t] += add;
      __syncthreads();
    }
    if (t < c2 && firstIdx == t) s_uniq[s_scan[t] - 1] = s_e[t];
    __syncthreads();
    if (t < c2) s_slotp[t] = s_scan[firstIdx] - 1;
    if (t == 0) {
      int K1 = (c2 > 0) ? s_scan[255] : 0;
      int kd = -1;
      for (int i = 0; i < K1; ++i) if (s_uniq[i] == TGT) { kd = i; break; }
      if (kd < 0) { s_uniq[K1] = TGT; kd = K1; K1++; }
      s_kv[0] = K1; s_kv[1] = kd;
    }
    for (int i = t; i < BMWORDS; i += 256) s_bm[i] = 0u;
    __syncthreads();
    int K1 = s_kv[0];
    for (int i = t; i < K1; i += 256) {
      int u = s_uniq[i];
      atomicOr(&s_bm[u >> 5], 1u << (u & 31));
    }
    __syncthreads();
    const int* esrc = eidx;
    const int4* edst4 = (const int4*)(eidx + N_EDGES);  // still L2-hot: no inv now
    for (int i = tid; i < N_EDGES / 4; i += nthreads) {
      int4 d = edst4[i];
      int dv[4] = {d.x, d.y, d.z, d.w};
#pragma unroll
      for (int j = 0; j < 4; ++j) {
        int u = dv[j];
        if ((s_bm[u >> 5] >> (u & 31)) & 1u) {   // exact: bit index == node id
          int k = 0;
          for (int q = 0; q < K1; ++q) if (s_uniq[q] == u) { k = q; break; }
          int p = atomicAdd(&w.cnt2[k], 1);
          if (p < ELMAX)                       // write-through: no release needed
            __hip_atomic_store(&w.l1src[k * ELMAX + p], esrc[4 * i + j],
                               __ATOMIC_RELAXED, __HIP_MEMORY_SCOPE_AGENT);
        }
      }
    }
  }
  gbar(w.cnt, BAR1, blk, false);

  // ========== stages D+E fused: ONE block per dst k (no per-dst join) ==========
  const int K1 = s_kv[0];
  if (blk >= K1) return;                       // idle blocks exit; F-join counts to K1
  {
    const int k = blk;
    const float4* W1v = (const float4*)w.W1T4;
    const float4* W2v = (const float4*)w.W2T4;
    const int ne = min((int)__hip_atomic_load(&w.cnt2[k], __ATOMIC_RELAXED,
                                              __HIP_MEMORY_SCOPE_AGENT), ELMAX);
    const int items = ne + 1;                  // edges + the dst node itself
    const int myNode = s_uniq[k];

    float* s_xsT = (float*)smem;               // 1024 f
    float* s_redS = (float*)(smem + 4096);     // 1024 f
    float* s_redD = (float*)(smem + 8192);     // 1024 f
    float* s_as1 = (float*)(smem + 12288);     // ROWS*8 f (persists into E)
    float* s_ad1 = (float*)(smem + 20512);     // ROWS*8 f (persists into E)
    const float4* xsT4 = (const float4*)s_xsT;

    // ---- stage D: all row-batches of this dst, sequential in one block ----
    for (int base = 0; base < items; base += 4) {
      int na = min(4, items - base);
      int nd[4];
#pragma unroll
      for (int i = 0; i < 4; ++i) {            // 4 independent index loads
        int it = base + i;
        nd[i] = (it < ne) ? w.l1src[k * ELMAX + it] : myNode;
      }
#pragma unroll
      for (int i = 0; i < 4; ++i)              // 4 independent row loads in flight
        s_xsT[t * 4 + i] = x[(size_t)nd[i] * 256 + t];
      __syncthreads();
      float a0 = 0.f, a1 = 0.f, a2 = 0.f, a3 = 0.f;
      for (int cc = 0; cc < 64; cc += 8) {
        float4 wreg[8];
#pragma unroll
        for (int j = 0; j < 8; ++j)            // 8 W loads issued before any use
          wreg[j] = W1v[(size_t)(cc + j) * 256 + t];
#pragma unroll
        for (int j = 0; j < 8; ++j) {
          float4 wv = wreg[j];
          int c4 = cc + j;
          float4 x0 = xsT4[4 * c4 + 0];
          float4 x1 = xsT4[4 * c4 + 1];
          float4 x2 = xsT4[4 * c4 + 2];
          float4 x3 = xsT4[4 * c4 + 3];
          a0 = fmaf(wv.x, x0.x, a0); a0 = fmaf(wv.y, x1.x, a0); a0 = fmaf(wv.z, x2.x, a0); a0 = fmaf(wv.w, x3.x, a0);
          a1 = fmaf(wv.x, x0.y, a1); a1 = fmaf(wv.y, x1.y, a1); a1 = fmaf(wv.z, x2.y, a1); a1 = fmaf(wv.w, x3.y, a1);
          a2 = fmaf(wv.x, x0.z, a2); a2 = fmaf(wv.y, x1.z, a2); a2 = fmaf(wv.z, x2.z, a2); a2 = fmaf(wv.w, x3.z, a2);
          a3 = fmaf(wv.x, x0.w, a3); a3 = fmaf(wv.y, x1.w, a3); a3 = fmaf(wv.z, x2.w, a3); a3 = fmaf(wv.w, x3.w, a3);
        }
      }
      float accs[4] = {a0, a1, a2, a3};
      for (int i = 0; i < na; ++i) {
        w.g_xw1[(size_t)(k * ROWS + base + i) * 256 + t] = accs[i];  // own-block reuse
        s_redS[i * 256 + t] = accs[i] * aS1[t];
        s_redD[i * 256 + t] = accs[i] * aD1[t];
      }
      __syncthreads();
      if (t < 32) {
        int i = t >> 3, h = t & 7;
        if (i < na) {
          float s = 0.f, dd = 0.f;
          for (int q = 0; q < 32; ++q) {
            s  += s_redS[i * 256 + h * 32 + q];
            dd += s_redD[i * 256 + h * 32 + q];
          }
          s_as1[(base + i) * 8 + h] = s;       // LDS, no global round-trip
          s_ad1[(base + i) * 8 + h] = dd;
        }
      }
      __syncthreads();
    }

    // ---- stage E: softmax + aggregate + bias + exact GELU + xw2 ----
    {
      float* s_p  = (float*)smem;              // 2048 f (overlays s_xsT+s_redS)
      float* s_h1 = (float*)(smem + 10240);    // 256 f (align 16)
      float* s_den = (float*)(smem + 11264);   // 8 f
      if (t < 8) {
        int h = t;
        float adst = s_ad1[ne * 8 + h];
        float m = -INFINITY;
        for (int j = 0; j < ne; ++j) {
          float e = s_as1[j * 8 + h] + adst;
          e = (e >= 0.f) ? e : 0.2f * e;
          m = fmaxf(m, e);
        }
        float den = 0.f;
        for (int j = 0; j < ne; ++j) {
          float e = s_as1[j * 8 + h] + adst;
          e = (e >= 0.f) ? e : 0.2f * e;
          float pp = expf(e - m);
          s_p[j * 8 + h] = pp;
          den += pp;
        }
        s_den[h] = den + 1e-16f;
      }
      __syncthreads();
      int h = t >> 5;
      float acc = 0.f;
      const float* xwb = w.g_xw1 + (size_t)(k * ROWS) * 256 + t;  // own writes
      for (int j0 = 0; j0 < ne; j0 += 8) {
        float tmp[8];
#pragma unroll
        for (int j = 0; j < 8; ++j)            // 8 gathers in flight
          tmp[j] = (j0 + j < ne) ? xwb[(size_t)(j0 + j) * 256] : 0.f;
#pragma unroll
        for (int j = 0; j < 8; ++j)
          if (j0 + j < ne) acc = fmaf(s_p[(j0 + j) * 8 + h], tmp[j], acc);
      }
      float o = (ne > 0) ? acc / s_den[h] : 0.f;
      o += b1[t];
      s_h1[t] = 0.5f * o * (1.f + erff(o * 0.70710678118654752440f));  // exact GELU
      __syncthreads();
      float a2s = 0.f;
      const float4* h1v = (const float4*)s_h1;
      for (int cc = 0; cc < 64; cc += 8) {
        float4 wreg[8];
#pragma unroll
        for (int j = 0; j < 8; ++j)
          wreg[j] = W2v[(size_t)(cc + j) * 256 + t];
#pragma unroll
        for (int j = 0; j < 8; ++j) {
          float4 wv = wreg[j];
          float4 hv = h1v[cc + j];
          a2s = fmaf(wv.x, hv.x, a2s); a2s = fmaf(wv.y, hv.y, a2s);
          a2s = fmaf(wv.z, hv.z, a2s); a2s = fmaf(wv.w, hv.w, a2s);
        }
      }
      w.g_xw2[k * 256 + t] = a2s;
      float* rS = (float*)(smem + 8192);       // free by now (s_redD region)
      float* rD = (float*)(smem + 9216);
      rS[t] = a2s * aS2[t];
      rD[t] = a2s * aD2[t];
      __syncthreads();
      if (t < 8) {
        float s = 0.f, dd = 0.f;
        for (int q = 0; q < 32; ++q) { s += rS[t * 32 + q]; dd += rD[t * 32 + q]; }
        w.g_as2[k * 8 + t] = s;
        w.g_ad2[k * 8 + t] = dd;
      }
    }

    // ---- global join (verified idiom, only K1~17 release ops total) ----
    __syncthreads();
    if (t == 0) {
      __threadfence();
      int old2 = __hip_atomic_fetch_add(&w.cnt[1], 1, __ATOMIC_ACQ_REL, __HIP_MEMORY_SCOPE_AGENT);
      s_winF = (old2 == K1 - 1);
    }
    __syncthreads();
    if (!s_winF) return;
    __threadfence();

    // ---- stage F: layer-2 attention for node TGT ----
    {
      float* s_p = (float*)smem;               // 2048 f
      float* s_den = (float*)(smem + 8192);    // 8 f
      int c2 = min(w.cnt[0], C2MAX);
      int kd = s_kv[1];
      if (t < 8) {
        float adst = w.g_ad2[kd * 8 + t];
        float m = -INFINITY;
        for (int j = 0; j < c2; ++j) {
          float e = w.g_as2[s_slotp[j] * 8 + t] + adst;
          e = (e >= 0.f) ? e : 0.2f * e;
          m = fmaxf(m, e);
        }
        float den = 0.f;
        for (int j = 0; j < c2; ++j) {
          float e = w.g_as2[s_slotp[j] * 8 + t] + adst;
          e = (e >= 0.f) ? e : 0.2f * e;
          float pp = expf(e - m);
          s_p[j * 8 + t] = pp;
          den += pp;
        }
        s_den[t] = den + 1e-16f;
      }
      __syncthreads();
      int h = t >> 5;
      float acc2 = 0.f;
      for (int j0 = 0; j0 < c2; j0 += 8) {
        float tmp[8];
#pragma unroll
        for (int j = 0; j < 8; ++j)
          tmp[j] = (j0 + j < c2) ? w.g_xw2[s_slotp[j0 + j] * 256 + t] : 0.f;
#pragma unroll
        for (int j = 0; j < 8; ++j)
          if (j0 + j < c2) acc2 = fmaf(s_p[(j0 + j) * 8 + h], tmp[j], acc2);
      }
      float o2 = (c2 > 0) ? acc2 / s_den[h] : 0.f;
      out[t] = o2 + b2[t];
    }
  }
}

extern "C" void kernel_launch(void* const* d_in, const int* in_sizes, int n_in,
                              void* d_out, int out_size, void* d_ws, size_t ws_size,
                              hipStream_t stream) {
  const float* x    = (const float*)d_in[0];
  const int*   eidx = (const int*)d_in[1];
  const float* W1   = (const float*)d_in[2];
  const float* aS1  = (const float*)d_in[3];
  const float* aD1  = (const float*)d_in[4];
  const float* b1   = (const float*)d_in[5];
  const float* W2   = (const float*)d_in[6];
  const float* aS2  = (const float*)d_in[7];
  const float* aD2  = (const float*)d_in[8];
  const float* b2   = (const float*)d_in[9];
  float* out = (float*)d_out;
  char*  ws  = (char*)d_ws;

  // zero cnt[2048] (incl. barrier areas) + cnt2[272] + fin_k[272]
  hipMemsetAsync(ws, 0, (2048 + 272 + 272) * sizeof(int), stream);

  k_all<<<dim3(GRID), dim3(256), 0, stream>>>(x, eidx, W1, W2, aS1, aD1, b1,
                                              aS2, aD2, b2, out, ws);
}